// Round 6
// baseline (9316.582 us; speedup 1.0000x reference)
//
#include <hip/hip_runtime.h>
#include <hip/hip_fp16.h>
#include <stdint.h>

#define ALPHA 0.3f

__device__ __forceinline__ float leaky(float v) { return v > 0.0f ? v : ALPHA * v; }
__device__ __forceinline__ float sigm(float v)  { return 1.0f / (1.0f + __expf(-v)); }
__device__ __forceinline__ float tanh_fast(float v) { return 1.0f - 2.0f / (1.0f + __expf(2.0f * v)); }
__device__ __forceinline__ __half2 u2h(unsigned u) { union { unsigned u; __half2 h; } c; c.u = u; return c.h; }

// ---------------------------------------------------------------------------
// Pack Wh (256x1024) and Wx (51x1024) fp32 -> fp16 k-pair-packed, gate-interleaved.
// Whp u32[idx], idx = kp*1024 + j*4 + g  = half2( Wh[2kp][g*256+j], Wh[2kp+1][g*256+j] )
// Wxp u32[i],   i   = fp*1024 + j*4 + g  = half2( Wx[2fp][g*256+j], Wx[2fp+1][g*256+j] ), f=51 -> 0
// ---------------------------------------------------------------------------
__global__ __launch_bounds__(256) void pack_w(
    const float* __restrict__ Wh, const float* __restrict__ Wx,
    unsigned* __restrict__ Whp, unsigned* __restrict__ Wxp) {
    int idx = blockIdx.x * 256 + threadIdx.x;
    if (idx < 128 * 1024) {
        int kp = idx >> 10, rem = idx & 1023;
        int j = rem >> 2, g = rem & 3;
        int col = g * 256 + j;
        float a = Wh[(2 * kp) * 1024 + col];
        float b = Wh[(2 * kp + 1) * 1024 + col];
        Whp[idx] = (unsigned)__half_as_ushort(__float2half(a))
                 | ((unsigned)__half_as_ushort(__float2half(b)) << 16);
    } else {
        int i = idx - 128 * 1024;   // grid sized exactly: i < 26*1024
        int fp = i >> 10, rem = i & 1023;
        int j = rem >> 2, g = rem & 3;
        int col = g * 256 + j;
        float a = Wx[(2 * fp) * 1024 + col];
        float b = (2 * fp + 1 < 51) ? Wx[(2 * fp + 1) * 1024 + col] : 0.0f;
        Wxp[i] = (unsigned)__half_as_ushort(__float2half(a))
               | ((unsigned)__half_as_ushort(__float2half(b)) << 16);
    }
}

// ---------------------------------------------------------------------------
// Fused conv1 -> conv2 -> partial dense dot. One block per batch element.
// (validated round 4 — unchanged; lstm dominates)
// ---------------------------------------------------------------------------
__global__ __launch_bounds__(256) void conv_kernel(
    const float* __restrict__ x,
    const float* __restrict__ k1, const float* __restrict__ b1,
    const float* __restrict__ k2, const float* __restrict__ b2,
    const float* __restrict__ Wd, const float* __restrict__ bd,
    float* __restrict__ out) {
    extern __shared__ unsigned char smem[];
    float* h1s = (float*)smem;                 // 65536 B
    float* xs  = (float*)(smem + 65536);       // 52848 B

    const int tid = threadIdx.x;
    const int b   = blockIdx.x;
    const float* xb = x + (size_t)b * (512 * 51);

    const int c1g = tid & 15;
    const int t1g = tid >> 4;
    float4 b1v = *(const float4*)&b1[c1g * 4];

    #pragma unroll
    for (int chunk = 0; chunk < 2; ++chunk) {
        const int tb   = chunk ? 128 : 0;
        const int rb_  = chunk ? 252 : 0;
        const int rows = chunk ? 259 : 255;
        {
            const float* src = xb + rb_ * 51;
            int total = rows * 51;
            int n4 = total >> 2;
            const float4* s4 = (const float4*)src;
            float4* d4 = (float4*)xs;
            for (int i = tid; i < n4; i += 256) d4[i] = s4[i];
            for (int i = (n4 << 2) + tid; i < total; i += 256) xs[i] = src[i];
        }
        __syncthreads();

        float acc[8][4];
        #pragma unroll
        for (int i = 0; i < 8; ++i) { acc[i][0]=0.f; acc[i][1]=0.f; acc[i][2]=0.f; acc[i][3]=0.f; }

        for (int w = 0; w < 5; ++w) {
            for (int f = 0; f < 51; ++f) {
                float4 wt = *(const float4*)&k1[(w * 51 + f) * 64 + c1g * 4];
                #pragma unroll
                for (int i = 0; i < 8; ++i) {
                    int t1 = tb + t1g * 8 + i;
                    int r = 2 * t1 + w - 4;
                    if (r >= rb_) {
                        float a = xs[(r - rb_) * 51 + f];
                        acc[i][0] += a * wt.x; acc[i][1] += a * wt.y;
                        acc[i][2] += a * wt.z; acc[i][3] += a * wt.w;
                    }
                }
            }
        }
        #pragma unroll
        for (int i = 0; i < 8; ++i) {
            int t1 = tb + t1g * 8 + i;
            float* dst = &h1s[t1 * 64 + c1g * 4];
            dst[0] = leaky(acc[i][0] + b1v.x);
            dst[1] = leaky(acc[i][1] + b1v.y);
            dst[2] = leaky(acc[i][2] + b1v.z);
            dst[3] = leaky(acc[i][3] + b1v.w);
        }
        __syncthreads();
    }

    const int c2g = tid & 31;
    const int t2g = tid >> 5;
    float acc2[16][4];
    #pragma unroll
    for (int i = 0; i < 16; ++i) { acc2[i][0]=0.f; acc2[i][1]=0.f; acc2[i][2]=0.f; acc2[i][3]=0.f; }

    for (int w = 0; w < 5; ++w) {
        for (int c1 = 0; c1 < 64; ++c1) {
            float4 wt = *(const float4*)&k2[(w * 64 + c1) * 128 + c2g * 4];
            #pragma unroll
            for (int i = 0; i < 16; ++i) {
                int t2 = t2g * 16 + i;
                int r = 2 * t2 + w - 4;
                if (r >= 0) {
                    float a = h1s[r * 64 + c1];
                    acc2[i][0] += a * wt.x; acc2[i][1] += a * wt.y;
                    acc2[i][2] += a * wt.z; acc2[i][3] += a * wt.w;
                }
            }
        }
    }

    float4 b2v = *(const float4*)&b2[c2g * 4];
    float p = 0.f;
    #pragma unroll
    for (int i = 0; i < 16; ++i) {
        int t2 = t2g * 16 + i;
        float4 wd = *(const float4*)&Wd[256 + t2 * 128 + c2g * 4];
        p += leaky(acc2[i][0] + b2v.x) * wd.x;
        p += leaky(acc2[i][1] + b2v.y) * wd.y;
        p += leaky(acc2[i][2] + b2v.z) * wd.z;
        p += leaky(acc2[i][3] + b2v.w) * wd.w;
    }

    float* red = xs;
    __syncthreads();
    red[tid] = p;
    __syncthreads();
    for (int s = 128; s > 0; s >>= 1) {
        if (tid < s) red[tid] += red[tid + s];
        __syncthreads();
    }
    if (tid == 0) out[b] = red[0] + bd[0];
}

// ---------------------------------------------------------------------------
// LSTM helpers (all compile-time indexed -> registers, rule #20 safe)
// ---------------------------------------------------------------------------
__device__ __forceinline__ void fma16(__half2 (&acc)[4][4], uint4 wq, uint4 hq) {
    __half2 hv[4] = {u2h(hq.x), u2h(hq.y), u2h(hq.z), u2h(hq.w)};
    __half2 wv[4] = {u2h(wq.x), u2h(wq.y), u2h(wq.z), u2h(wq.w)};
    #pragma unroll
    for (int r = 0; r < 4; ++r)
        #pragma unroll
        for (int g = 0; g < 4; ++g)
            acc[r][g] = __hfma2(hv[r], wv[g], acc[r][g]);
}

__device__ __forceinline__ void pub2(const __half2 (&a0)[4], const __half2 (&a1)[4],
                                     float* rb, int tid) {
    #pragma unroll
    for (int g = 0; g < 4; ++g) {
        rb[g * 516 + tid]       = __low2float(a0[g]) + __high2float(a0[g]);
        rb[(4 + g) * 516 + tid] = __low2float(a1[g]) + __high2float(a1[g]);
    }
}

__device__ __forceinline__ void gate2(const __half2 (&a0)[4], const __half2 (&a1)[4],
                                      const float* rb, int or_tid,
                                      float bz0, float bz1, float bz2, float bz3,
                                      float (&cc)[2], float (&hn)[2],
                                      unsigned short* h16s, int j, int mr0) {
    #pragma unroll
    for (int rr = 0; rr < 2; ++rr) {
        const __half2* a = rr ? a1 : a0;     // rr unrolled -> compile-time
        float zi = __low2float(a[0]) + __high2float(a[0]) + rb[(rr * 4 + 0) * 516 + or_tid] + bz0;
        float zf = __low2float(a[1]) + __high2float(a[1]) + rb[(rr * 4 + 1) * 516 + or_tid] + bz1;
        float zg = __low2float(a[2]) + __high2float(a[2]) + rb[(rr * 4 + 2) * 516 + or_tid] + bz2;
        float zo = __low2float(a[3]) + __high2float(a[3]) + rb[(rr * 4 + 3) * 516 + or_tid] + bz3;
        float iv = sigm(zi);
        float fv = sigm(zf);
        float gv = tanh_fast(zg);
        float ov = sigm(zo);
        cc[rr] = fv * cc[rr] + iv * gv;
        hn[rr] = ov * tanh_fast(cc[rr]);
        h16s[(j >> 1) * 8 + (mr0 + rr) * 2 + (j & 1)] = __half_as_ushort(__float2half(hn[rr]));
    }
}

// ---------------------------------------------------------------------------
// Persistent LSTM: 256 blocks x 512 threads x 4 batch rows.
// k-split: waves 0-3 (grp 0) do kp 0..63 + fp 0..12; waves 4-7 (grp 1) do
// kp 64..127 + fp 13..25. Partial sums exchanged via rb[8][516] in LDS;
// grp g finishes gates for batch rows {2g, 2g+1}.
// Streamed Wh uses an explicit 8-deep uint4 register pipeline (MLP=8).
// LDS: wx_l 106496 | h16 2048 | xt16 416 | rb 16512  = 125472 B -> 1 block/CU
// ---------------------------------------------------------------------------
__global__ __launch_bounds__(512) void lstm_kernel(
    const float* __restrict__ x,
    const uint4*  __restrict__ Whp,    // [kp*256 + j] -> 4 gates (half2 pairs)
    const uint4*  __restrict__ Wxp,    // [fp*256 + j]
    const float*  __restrict__ bl,
    const float*  __restrict__ Wd,
    float* __restrict__ out) {
    extern __shared__ unsigned char smem[];
    unsigned* wx_l = (unsigned*)smem;                       // 106496 B
    unsigned* h16  = (unsigned*)(smem + 106496);            //   2048 B
    unsigned* xt16 = (unsigned*)(smem + 108544);            //    416 B
    float*    rb   = (float*)   (smem + 108960);            //  16512 B

    const int tid = threadIdx.x;
    const int j   = tid & 255;
    const int grp = tid >> 8;          // 0 or 1 (wave-uniform)
    const int b0  = blockIdx.x * 4;
    const int k0  = grp * 64;          // kp base
    const int f0  = grp * 13;          // fp base
    const int mr0 = grp * 2;           // my gate rows: mr0, mr0+1

    {
        uint4* d = (uint4*)wx_l;
        for (int i = tid; i < 26 * 256; i += 512) d[i] = Wxp[i];
    }
    h16[tid] = 0;
    if (tid < 104) xt16[tid] = 0;      // f=51 hi-half stays 0 forever
    const float bz0 = bl[j], bz1 = bl[j + 256], bz2 = bl[j + 512], bz3 = bl[j + 768];
    float cc[2] = {0.f, 0.f};
    float hn[2] = {0.f, 0.f};
    unsigned short* h16s  = (unsigned short*)h16;
    unsigned short* xt16s = (unsigned short*)xt16;

    // x prefetch: thread tid<204 (grp 0) owns (row rx, feature fx)
    const int fx = tid >> 2, rx = tid & 3;
    const float* xptr = x + ((size_t)(b0 + rx) * 512) * 51 + fx;
    float xpre = (tid < 204) ? xptr[0] : 0.0f;
    __syncthreads();

    for (int t = 0; t < 512; ++t) {
        if (tid < 204)
            xt16s[(fx >> 1) * 8 + rx * 2 + (fx & 1)] = __half_as_ushort(__float2half(xpre));
        __syncthreads();   // A: xt16 + h16 (written post-B last iter) published

        float xnext = 0.0f;
        if (tid < 204 && t + 1 < 512) xnext = xptr[(t + 1) * 51];

        __half2 acc[4][4];
        #pragma unroll
        for (int r = 0; r < 4; ++r)
            #pragma unroll
            for (int g = 0; g < 4; ++g) acc[r][g] = u2h(0u);

        // prologue: fill the 8-deep pipeline (flies during x-projection)
        const uint4* wbase = Whp + (size_t)k0 * 256 + j;
        uint4 wbuf[8];
        #pragma unroll
        for (int i = 0; i < 8; ++i) wbuf[i] = wbase[i * 256];

        // x-projection (Wx in LDS; xt16 broadcast)
        #pragma unroll
        for (int ff = 0; ff < 13; ++ff) {
            int fp = f0 + ff;
            uint4 wq = ((const uint4*)wx_l)[fp * 256 + j];
            uint4 hq = *(const uint4*)&xt16[fp * 4];
            fma16(acc, wq, hq);
        }

        // streamed Wh: consume wbuf[kk], immediately reload kk+8
        for (int kb = 0; kb < 56; kb += 8) {
            #pragma unroll
            for (int kk = 0; kk < 8; ++kk) {
                uint4 wq = wbuf[kk];
                wbuf[kk] = wbase[(kb + 8 + kk) * 256];
                uint4 hq = *(const uint4*)&h16[(k0 + kb + kk) * 4];
                fma16(acc, wq, hq);
            }
        }
        #pragma unroll
        for (int kk = 0; kk < 8; ++kk) {
            uint4 wq = wbuf[kk];
            uint4 hq = *(const uint4*)&h16[(k0 + 56 + kk) * 4];
            fma16(acc, wq, hq);
        }

        // publish the other group's rows (wave-uniform branch, static indices)
        if (grp == 0) pub2(acc[2], acc[3], rb, tid);
        else          pub2(acc[0], acc[1], rb, tid);
        __syncthreads();   // B: rb complete; also orders xt16/h16 read-write

        // finish gates for my 2 rows (other half of sums from rb[tid^256])
        if (grp == 0) gate2(acc[0], acc[1], rb, tid ^ 256, bz0, bz1, bz2, bz3,
                            cc, hn, h16s, j, mr0);
        else          gate2(acc[2], acc[3], rb, tid ^ 256, bz0, bz1, bz2, bz3,
                            cc, hn, h16s, j, mr0);
        xpre = xnext;
        // next iteration's barrier A publishes h16 before any read
    }

    // out[b0+r] += leaky(h_r) . Wd  (rows split across groups)
    const float pw = Wd[j];
    float p0 = leaky(hn[0]) * pw;
    float p1 = leaky(hn[1]) * pw;
    __syncthreads();                    // last gate-phase rb reads done
    rb[(mr0 + 0) * 516 + j] = p0;
    rb[(mr0 + 1) * 516 + j] = p1;
    __syncthreads();
    const int rid = tid >> 7;           // 0..3
    const int l   = tid & 127;
    float v = rb[rid * 516 + l] + rb[rid * 516 + l + 128];
    rb[rid * 516 + l] = v;
    __syncthreads();
    if (l < 64) {                       // threads rid*128+0..63 = one full wave
        v = rb[rid * 516 + l] + rb[rid * 516 + l + 64];
        #pragma unroll
        for (int off = 32; off; off >>= 1) v += __shfl_down(v, off, 64);
        if (l == 0) out[b0 + rid] += v;
    }
}

// ---------------------------------------------------------------------------
extern "C" void kernel_launch(void* const* d_in, const int* in_sizes, int n_in,
                              void* d_out, int out_size, void* d_ws, size_t ws_size,
                              hipStream_t stream) {
    const float* x   = (const float*)d_in[0];
    const float* Wx  = (const float*)d_in[1];
    const float* Wh  = (const float*)d_in[2];
    const float* bl  = (const float*)d_in[3];
    const float* k1  = (const float*)d_in[4];
    const float* b1  = (const float*)d_in[5];
    const float* k2  = (const float*)d_in[6];
    const float* b2  = (const float*)d_in[7];
    const float* Wd  = (const float*)d_in[8];
    const float* bd  = (const float*)d_in[9];
    float* out = (float*)d_out;

    unsigned* Whp = (unsigned*)d_ws;           // 131072 u32 (512 KB)
    unsigned* Wxp = Whp + 128 * 1024;          //  26624 u32 (104 KB)

    const int conv_smem = 65536 + 13212 * 4;                 // 118384 B
    const int lstm_smem = 106496 + 2048 + 416 + 16512;       // 125472 B

    // Idempotent host-side attribute set — graph-capture-safe.
    hipFuncSetAttribute((const void*)conv_kernel,
                        hipFuncAttributeMaxDynamicSharedMemorySize, conv_smem);
    hipFuncSetAttribute((const void*)lstm_kernel,
                        hipFuncAttributeMaxDynamicSharedMemorySize, lstm_smem);

    pack_w<<<616, 256, 0, stream>>>(Wh, Wx, Whp, Wxp);
    conv_kernel<<<1024, 256, conv_smem, stream>>>(x, k1, b1, k2, b2, Wd, bd, out);
    lstm_kernel<<<256, 512, lstm_smem, stream>>>(x, (const uint4*)Whp, (const uint4*)Wxp,
                                                 bl, Wd, out);
}